// Round 1
// baseline (639.220 us; speedup 1.0000x reference)
//
#include <hip/hip_runtime.h>

#define BATCH 16
#define LSEQ 2048
#define DIM 64
#define TQ 16
#define LDST 2052      // 2048 + 4 pad: row stride mod 32 = 4 -> max 2-way bank alias (free)
#define EPSV 1e-8f

typedef float f4 __attribute__((ext_vector_type(4)));
typedef _Float16 h8 __attribute__((ext_vector_type(8)));
typedef int i4t __attribute__((ext_vector_type(4)));

__device__ inline h8 cvt_h8(f4 a, f4 b) {
    h8 r;
    r[0] = (_Float16)a[0]; r[1] = (_Float16)a[1];
    r[2] = (_Float16)a[2]; r[3] = (_Float16)a[3];
    r[4] = (_Float16)b[0]; r[5] = (_Float16)b[1];
    r[6] = (_Float16)b[2]; r[7] = (_Float16)b[3];
    return r;
}

__global__ __launch_bounds__(512)
void attn_kernel(const float* __restrict__ q, const float* __restrict__ k,
                 const float* __restrict__ v, const int* __restrict__ mask,
                 float* __restrict__ out, float* __restrict__ attn)
{
    __shared__ float s_p[TQ][LDST];      // raw scores -> masked p -> normalized p
    __shared__ float oacc[8][TQ * 16];   // PV partial accumulators (8 waves)

    const int b    = blockIdx.y;
    const int q0   = blockIdx.x * TQ;
    const int tid  = threadIdx.x;
    const int w    = tid >> 6;       // wave 0..7
    const int lane = tid & 63;
    const int quad = lane >> 4;      // 0..3
    const int m16  = lane & 15;      // 0..15

    const float* qp = q + ((size_t)b * LSEQ + q0) * DIM;
    const float* kp = k + (size_t)b * LSEQ * DIM;
    const float* vp = v + (size_t)b * LSEQ * DIM;

    // ---- Q A-fragments (A[m=lane&15][kd=quad*8+j], two K=32 halves of D=64) ----
    const float* qrow = qp + m16 * DIM + quad * 8;
    h8 aq0 = cvt_h8(*(const f4*)(qrow),      *(const f4*)(qrow + 4));
    h8 aq1 = cvt_h8(*(const f4*)(qrow + 32), *(const f4*)(qrow + 36));

    // ---- Phase B: S = Q K^T / 8 -> LDS. Wave w owns 16-col tiles t = w, w+8, ... ----
    for (int t = w; t < LSEQ / 16; t += 8) {
        const int c = t * 16;
        const float* krow = kp + (size_t)(c + m16) * DIM + quad * 8; // B[kd][n=c+m16] = K[c+m16][kd]
        h8 bk0 = cvt_h8(*(const f4*)(krow),      *(const f4*)(krow + 4));
        h8 bk1 = cvt_h8(*(const f4*)(krow + 32), *(const f4*)(krow + 36));
        f4 acc = {0.f, 0.f, 0.f, 0.f};
        acc = __builtin_amdgcn_mfma_f32_16x16x32_f16(aq0, bk0, acc, 0, 0, 0);
        acc = __builtin_amdgcn_mfma_f32_16x16x32_f16(aq1, bk1, acc, 0, 0, 0);
        // D layout: row = quad*4 + r, col = m16
        #pragma unroll
        for (int r = 0; r < 4; ++r)
            s_p[quad * 4 + r][c + m16] = acc[r] * 0.125f;
    }
    __syncthreads();

    // ---- Phase C/D: per-wave rows 2w, 2w+1: max -> exp -> mask -> sums -> write attn ----
    #pragma unroll
    for (int rr = 0; rr < 2; ++rr) {
        const int row = 2 * w + rr;
        float mx = -1e30f;
        #pragma unroll
        for (int j = 0; j < 8; ++j) {
            f4 sv = *(const f4*)(&s_p[row][lane * 4 + 256 * j]);
            mx = fmaxf(mx, fmaxf(fmaxf(sv[0], sv[1]), fmaxf(sv[2], sv[3])));
        }
        #pragma unroll
        for (int off = 32; off >= 1; off >>= 1)
            mx = fmaxf(mx, __shfl_xor(mx, off));

        const int* mrow = mask + ((size_t)b * LSEQ + q0 + row) * LSEQ;
        float sa = 0.f, sk = 0.f;
        #pragma unroll
        for (int j = 0; j < 8; ++j) {
            const int c = lane * 4 + 256 * j;
            f4 sv = *(const f4*)(&s_p[row][c]);
            i4t mv = __builtin_nontemporal_load((const i4t*)(mrow + c));
            f4 pv;
            #pragma unroll
            for (int e = 0; e < 4; ++e) {
                float p = __expf(sv[e] - mx);
                sa += p;
                pv[e] = mv[e] ? 0.f : p;
                sk += pv[e];
            }
            *(f4*)(&s_p[row][c]) = pv;
        }
        #pragma unroll
        for (int off = 32; off >= 1; off >>= 1) {
            sa += __shfl_xor(sa, off);
            sk += __shfl_xor(sk, off);
        }
        const float inv_d = 1.f / (sk + EPSV * sa);

        float* arow = attn + ((size_t)b * LSEQ + q0 + row) * LSEQ;
        #pragma unroll
        for (int j = 0; j < 8; ++j) {
            const int c = lane * 4 + 256 * j;
            f4 pv = *(const f4*)(&s_p[row][c]);
            pv = pv * inv_d;
            __builtin_nontemporal_store(pv, (f4*)(&arow[c]));
            *(f4*)(&s_p[row][c]) = pv;   // normalized p for PV
        }
    }
    __syncthreads();

    // ---- Phase E: O = P V. Wave w: d-tile = w>>1, k-half = w&1 ----
    {
        const int dt = w >> 1;
        const int kh = w & 1;
        f4 acc = {0.f, 0.f, 0.f, 0.f};
        for (int kb0 = kh * 1024; kb0 < kh * 1024 + 1024; kb0 += 32) {
            const int kk = kb0 + quad * 8;                      // A[m=m16][k=kk+j]
            h8 af = cvt_h8(*(const f4*)(&s_p[m16][kk]), *(const f4*)(&s_p[m16][kk + 4]));
            const float* vcol = vp + (size_t)kk * DIM + dt * 16 + m16; // B[k][n=dt*16+m16]
            h8 bf;
            #pragma unroll
            for (int j = 0; j < 8; ++j)
                bf[j] = (_Float16)vcol[j * DIM];
            acc = __builtin_amdgcn_mfma_f32_16x16x32_f16(af, bf, acc, 0, 0, 0);
        }
        #pragma unroll
        for (int r = 0; r < 4; ++r)
            oacc[w][(quad * 4 + r) * 16 + m16] = acc[r];
    }
    __syncthreads();

    // ---- Combine k-halves, write O (coalesced) ----
    float* ob = out + ((size_t)b * LSEQ + q0) * DIM;
    #pragma unroll
    for (int it = 0; it < 2; ++it) {
        const int idx = tid + it * 512;      // 0..1023 over 16x64
        const int row = idx >> 6;
        const int d   = idx & 63;
        const int dt2 = d >> 4, dc = d & 15;
        ob[row * DIM + d] = oacc[2 * dt2][row * 16 + dc] + oacc[2 * dt2 + 1][row * 16 + dc];
    }
}

extern "C" void kernel_launch(void* const* d_in, const int* in_sizes, int n_in,
                              void* d_out, int out_size, void* d_ws, size_t ws_size,
                              hipStream_t stream) {
    const float* q = (const float*)d_in[0];
    const float* k = (const float*)d_in[1];
    const float* v = (const float*)d_in[2];
    const int* mask = (const int*)d_in[3];
    float* out = (float*)d_out;                                   // [16,2048,64]
    float* attn = out + (size_t)BATCH * LSEQ * DIM;               // [16,2048,2048]
    dim3 grid(LSEQ / TQ, BATCH);
    attn_kernel<<<grid, 512, 0, stream>>>(q, k, v, mask, out, attn);
}

// Round 2
// 580.944 us; speedup vs baseline: 1.1003x; 1.1003x over previous
//
#include <hip/hip_runtime.h>

#define BATCH 16
#define LSEQ 2048
#define DIM 64
#define TQ 16
#define SSTRIDE 2056   // halfs; 16B-aligned row stride; bank-balanced for phase-E b128 reads
#define EPSV 1e-8f

typedef float f4 __attribute__((ext_vector_type(4)));
typedef _Float16 h4 __attribute__((ext_vector_type(4)));
typedef _Float16 h8 __attribute__((ext_vector_type(8)));
typedef int i4t __attribute__((ext_vector_type(4)));

__device__ inline h8 cvt_h8(f4 a, f4 b) {
    h8 r;
    r[0] = (_Float16)a[0]; r[1] = (_Float16)a[1];
    r[2] = (_Float16)a[2]; r[3] = (_Float16)a[3];
    r[4] = (_Float16)b[0]; r[5] = (_Float16)b[1];
    r[6] = (_Float16)b[2]; r[7] = (_Float16)b[3];
    return r;
}

__global__ __launch_bounds__(512, 4)
void attn_kernel(const float* __restrict__ q, const float* __restrict__ k,
                 const float* __restrict__ v, const int* __restrict__ mask,
                 float* __restrict__ out, float* __restrict__ attn)
{
    // fp16 score/p tile: 16 x 2056 halfs = 64.3 KB (fp32 tile was 131 KB -> 1 blk/CU)
    __shared__ __align__(16) _Float16 s_p[TQ][SSTRIDE];
    __shared__ float oacc[8][TQ * 16];   // PV partials (8 waves)
    __shared__ float s_inv[TQ];          // per-row 1/(sum+eps), folded into O at the end

    const int b    = blockIdx.y;
    const int q0   = blockIdx.x * TQ;
    const int tid  = threadIdx.x;
    const int w    = tid >> 6;
    const int lane = tid & 63;
    const int quad = lane >> 4;
    const int m16  = lane & 15;

    const float* qp = q + ((size_t)b * LSEQ + q0) * DIM;
    const float* kp = k + (size_t)b * LSEQ * DIM;
    const float* vp = v + (size_t)b * LSEQ * DIM;

    // ---- Q A-fragments: A[m=m16][kd=quad*8+j], two K=32 halves of D=64 ----
    const float* qrow = qp + m16 * DIM + quad * 8;
    h8 aq0 = cvt_h8(*(const f4*)(qrow),      *(const f4*)(qrow + 4));
    h8 aq1 = cvt_h8(*(const f4*)(qrow + 32), *(const f4*)(qrow + 36));

    // ---- Phase B: S = Q K^T / 8 -> LDS (fp16). Wave w owns 16-col tiles t = w, w+8, ...
    for (int t = w; t < LSEQ / 16; t += 8) {
        const int c = t * 16;
        const float* krow = kp + (size_t)(c + m16) * DIM + quad * 8;
        h8 bk0 = cvt_h8(*(const f4*)(krow),      *(const f4*)(krow + 4));
        h8 bk1 = cvt_h8(*(const f4*)(krow + 32), *(const f4*)(krow + 36));
        f4 acc = {0.f, 0.f, 0.f, 0.f};
        acc = __builtin_amdgcn_mfma_f32_16x16x32_f16(aq0, bk0, acc, 0, 0, 0);
        acc = __builtin_amdgcn_mfma_f32_16x16x32_f16(aq1, bk1, acc, 0, 0, 0);
        #pragma unroll
        for (int r = 0; r < 4; ++r)
            s_p[quad * 4 + r][c + m16] = (_Float16)(acc[r] * 0.125f);
    }
    __syncthreads();

    // ---- Phase C/D: wave w owns rows 2w, 2w+1 ----
    #pragma unroll
    for (int rr = 0; rr < 2; ++rr) {
        const int row = 2 * w + rr;

        // pass 1: row max
        float mx = -1e30f;
        #pragma unroll
        for (int j = 0; j < 8; ++j) {
            h4 hv = *(const h4*)(&s_p[row][lane * 4 + 256 * j]);
            mx = fmaxf(mx, fmaxf(fmaxf((float)hv[0], (float)hv[1]),
                                 fmaxf((float)hv[2], (float)hv[3])));
        }
        #pragma unroll
        for (int off = 32; off >= 1; off >>= 1)
            mx = fmaxf(mx, __shfl_xor(mx, off));

        // pass 2: exp + mask; keep masked un-normalized p in regs (h4 x 8 = 16 VGPRs)
        const int* mrow = mask + ((size_t)b * LSEQ + q0 + row) * LSEQ;
        float sa = 0.f, sk = 0.f;
        h4 pk[8];
        #pragma unroll
        for (int j = 0; j < 8; ++j) {
            const int c = lane * 4 + 256 * j;
            h4 hv = *(const h4*)(&s_p[row][c]);
            i4t mv = __builtin_nontemporal_load((const i4t*)(mrow + c));
            #pragma unroll
            for (int e = 0; e < 4; ++e) {
                float p = __expf((float)hv[e] - mx);
                sa += p;
                float pm = mv[e] ? 0.f : p;
                sk += pm;
                pk[j][e] = (_Float16)pm;
            }
        }
        #pragma unroll
        for (int off = 32; off >= 1; off >>= 1) {
            sa += __shfl_xor(sa, off);
            sk += __shfl_xor(sk, off);
        }
        const float inv_d = 1.f / (sk + EPSV * sa);
        if (lane == 0) s_inv[row] = inv_d;

        // pass 3: store p (fp16) to LDS for PV; store normalized attn (fp32) to HBM
        float* arow = attn + ((size_t)b * LSEQ + q0 + row) * LSEQ;
        #pragma unroll
        for (int j = 0; j < 8; ++j) {
            const int c = lane * 4 + 256 * j;
            *(h4*)(&s_p[row][c]) = pk[j];
            f4 pv;
            #pragma unroll
            for (int e = 0; e < 4; ++e) pv[e] = inv_d * (float)pk[j][e];
            __builtin_nontemporal_store(pv, (f4*)(&arow[c]));
        }
    }
    __syncthreads();

    // ---- Phase E: O_unnorm = P V. Wave w: d-tile = w>>1, k-half = w&1 ----
    {
        const int dt = w >> 1;
        const int kh = w & 1;
        f4 acc = {0.f, 0.f, 0.f, 0.f};
        for (int kb0 = kh * 1024; kb0 < kh * 1024 + 1024; kb0 += 32) {
            const int kk = kb0 + quad * 8;                 // A[m=m16][k=kk+j]
            h8 af = *(const h8*)(&s_p[m16][kk]);           // direct fp16 frag, no cvt
            const float* vcol = vp + (size_t)kk * DIM + dt * 16 + m16;
            h8 bf;
            #pragma unroll
            for (int j = 0; j < 8; ++j)
                bf[j] = (_Float16)vcol[j * DIM];
            acc = __builtin_amdgcn_mfma_f32_16x16x32_f16(af, bf, acc, 0, 0, 0);
        }
        #pragma unroll
        for (int r = 0; r < 4; ++r)
            oacc[w][(quad * 4 + r) * 16 + m16] = acc[r];
    }
    __syncthreads();

    // ---- Combine k-halves, scale by inv_d[row], write O ----
    float* ob = out + ((size_t)b * LSEQ + q0) * DIM;
    #pragma unroll
    for (int it = 0; it < 2; ++it) {
        const int idx = tid + it * 512;      // 0..1023 over 16x64
        const int row = idx >> 6;
        const int d   = idx & 63;
        const int dt2 = d >> 4, dc = d & 15;
        ob[row * DIM + d] = s_inv[row] *
            (oacc[2 * dt2][row * 16 + dc] + oacc[2 * dt2 + 1][row * 16 + dc]);
    }
}

extern "C" void kernel_launch(void* const* d_in, const int* in_sizes, int n_in,
                              void* d_out, int out_size, void* d_ws, size_t ws_size,
                              hipStream_t stream) {
    const float* q = (const float*)d_in[0];
    const float* k = (const float*)d_in[1];
    const float* v = (const float*)d_in[2];
    const int* mask = (const int*)d_in[3];
    float* out = (float*)d_out;                                   // [16,2048,64]
    float* attn = out + (size_t)BATCH * LSEQ * DIM;               // [16,2048,2048]
    dim3 grid(LSEQ / TQ, BATCH);
    attn_kernel<<<grid, 512, 0, stream>>>(q, k, v, mask, out, attn);
}

// Round 3
// 536.575 us; speedup vs baseline: 1.1913x; 1.0827x over previous
//
#include <hip/hip_runtime.h>

#define BATCH 16
#define LSEQ 2048
#define DIM 64
#define TQ 16
#define SSTRIDE 2056   // halfs; 16B-aligned row stride
#define EPSV 1e-8f

typedef float f4 __attribute__((ext_vector_type(4)));
typedef _Float16 h4 __attribute__((ext_vector_type(4)));
typedef _Float16 h8 __attribute__((ext_vector_type(8)));
typedef int i4t __attribute__((ext_vector_type(4)));

__device__ inline h8 cvt_h8(f4 a, f4 b) {
    h8 r;
    r[0] = (_Float16)a[0]; r[1] = (_Float16)a[1];
    r[2] = (_Float16)a[2]; r[3] = (_Float16)a[3];
    r[4] = (_Float16)b[0]; r[5] = (_Float16)b[1];
    r[6] = (_Float16)b[2]; r[7] = (_Float16)b[3];
    return r;
}

// ---- preprocess: K fp32 -> fp16 row-major (straight cvt, coalesced) ----
__global__ __launch_bounds__(256)
void cvt_k_kernel(const float* __restrict__ k, _Float16* __restrict__ kh) {
    const int idx = blockIdx.x * 256 + threadIdx.x;   // f4 index; total 524288
    f4 v = ((const f4*)k)[idx];
    h4 h;
    #pragma unroll
    for (int e = 0; e < 4; ++e) h[e] = (_Float16)v[e];
    ((h4*)kh)[idx] = h;
}

// ---- preprocess: V fp32 [b][k][d] -> fp16 transposed Vt [b][d][k] ----
__global__ __launch_bounds__(256)
void tr_v_kernel(const float* __restrict__ v, _Float16* __restrict__ vt) {
    __shared__ float tile[64][65];
    const int b = blockIdx.y, k0 = blockIdx.x * 64, t = threadIdx.x;
    const float* vb = v + ((size_t)b * LSEQ + k0) * DIM;
    #pragma unroll
    for (int p = 0; p < 4; ++p) {
        const int row = p * 16 + (t >> 4), c4 = (t & 15) * 4;
        f4 val = *(const f4*)(vb + row * DIM + c4);
        #pragma unroll
        for (int e = 0; e < 4; ++e) tile[row][c4 + e] = val[e];
    }
    __syncthreads();
    _Float16* vtb = vt + (size_t)b * DIM * LSEQ;
    #pragma unroll
    for (int p = 0; p < 4; ++p) {
        const int d = p * 16 + (t >> 4), k4 = (t & 15) * 4;
        h4 h;
        #pragma unroll
        for (int e = 0; e < 4; ++e) h[e] = (_Float16)tile[k4 + e][d];
        *(h4*)(vtb + (size_t)d * LSEQ + k0 + k4) = h;
    }
}

// ---- main kernel (fast path: fp16 Kh + transposed fp16 Vt) ----
__global__ __launch_bounds__(512, 4)
void attn_kernel(const float* __restrict__ q, const _Float16* __restrict__ kh,
                 const _Float16* __restrict__ vt, const int* __restrict__ mask,
                 float* __restrict__ out, float* __restrict__ attn)
{
    __shared__ __align__(16) _Float16 s_p[TQ][SSTRIDE];  // scores -> masked p (fp16)
    __shared__ float oacc[8][TQ * 16];
    __shared__ float s_inv[TQ];

    const int b    = blockIdx.y;
    const int q0   = blockIdx.x * TQ;
    const int tid  = threadIdx.x;
    const int w    = tid >> 6;
    const int lane = tid & 63;
    const int quad = lane >> 4;
    const int m16  = lane & 15;

    // Q A-fragments (fp32 -> h8 once)
    const float* qrow = q + ((size_t)b * LSEQ + q0 + m16) * DIM + quad * 8;
    h8 aq0 = cvt_h8(*(const f4*)(qrow),      *(const f4*)(qrow + 4));
    h8 aq1 = cvt_h8(*(const f4*)(qrow + 32), *(const f4*)(qrow + 36));

    // ---- Phase B: S = Q K^T / 8 -> LDS fp16. One 16B load per B-fragment half.
    for (int t = w; t < LSEQ / 16; t += 8) {
        const int c = t * 16;
        const _Float16* krow = kh + ((size_t)b * LSEQ + c + m16) * DIM + quad * 8;
        h8 bk0 = *(const h8*)(krow);
        h8 bk1 = *(const h8*)(krow + 32);
        f4 acc = {0.f, 0.f, 0.f, 0.f};
        acc = __builtin_amdgcn_mfma_f32_16x16x32_f16(aq0, bk0, acc, 0, 0, 0);
        acc = __builtin_amdgcn_mfma_f32_16x16x32_f16(aq1, bk1, acc, 0, 0, 0);
        #pragma unroll
        for (int r = 0; r < 4; ++r)
            s_p[quad * 4 + r][c + m16] = (_Float16)(acc[r] * 0.125f);
    }
    __syncthreads();

    // ---- Phase C/D: wave w owns rows 2w, 2w+1. No max pass (|s|<=8, fp16 relative
    // precision is scale-invariant and renorm cancels the scale).
    #pragma unroll
    for (int rr = 0; rr < 2; ++rr) {
        const int row = 2 * w + rr;
        const int* mrow = mask + ((size_t)b * LSEQ + q0 + row) * LSEQ;

        i4t mv[8];
        #pragma unroll
        for (int j = 0; j < 8; ++j)
            mv[j] = __builtin_nontemporal_load((const i4t*)(mrow + lane * 4 + 256 * j));

        float sa = 0.f, sk = 0.f;
        h4 pk[8];
        #pragma unroll
        for (int j = 0; j < 8; ++j) {
            h4 hv = *(const h4*)(&s_p[row][lane * 4 + 256 * j]);
            #pragma unroll
            for (int e = 0; e < 4; ++e) {
                float p = __expf((float)hv[e]);
                sa += p;
                float pm = mv[j][e] ? 0.f : p;
                sk += pm;
                pk[j][e] = (_Float16)pm;
            }
        }
        #pragma unroll
        for (int off = 32; off >= 1; off >>= 1) {
            sa += __shfl_xor(sa, off);
            sk += __shfl_xor(sk, off);
        }
        const float inv_d = 1.f / (sk + EPSV * sa);
        if (lane == 0) s_inv[row] = inv_d;

        float* arow = attn + ((size_t)b * LSEQ + q0 + row) * LSEQ;
        #pragma unroll
        for (int j = 0; j < 8; ++j) {
            const int c = lane * 4 + 256 * j;
            *(h4*)(&s_p[row][c]) = pk[j];
            f4 pv;
            #pragma unroll
            for (int e = 0; e < 4; ++e) pv[e] = inv_d * (float)pk[j][e];
            __builtin_nontemporal_store(pv, (f4*)(&arow[c]));
        }
    }
    __syncthreads();

    // ---- Phase E: O_unnorm = P V via Vt. One 16B load per B-fragment.
    {
        const int dt = w >> 1;
        const int kh_ = w & 1;
        const _Float16* vtr = vt + ((size_t)b * DIM + dt * 16 + m16) * LSEQ;
        f4 acc = {0.f, 0.f, 0.f, 0.f};
        for (int kb0 = kh_ * 1024; kb0 < kh_ * 1024 + 1024; kb0 += 32) {
            const int kk = kb0 + quad * 8;
            h8 af = *(const h8*)(&s_p[m16][kk]);
            h8 bf = *(const h8*)(vtr + kk);
            acc = __builtin_amdgcn_mfma_f32_16x16x32_f16(af, bf, acc, 0, 0, 0);
        }
        #pragma unroll
        for (int r = 0; r < 4; ++r)
            oacc[w][(quad * 4 + r) * 16 + m16] = acc[r];
    }
    __syncthreads();

    float* ob = out + ((size_t)b * LSEQ + q0) * DIM;
    #pragma unroll
    for (int it = 0; it < 2; ++it) {
        const int idx = tid + it * 512;
        const int row = idx >> 6;
        const int d   = idx & 63;
        const int dt2 = d >> 4, dc = d & 15;
        ob[row * DIM + d] = s_inv[row] *
            (oacc[2 * dt2][row * 16 + dc] + oacc[2 * dt2 + 1][row * 16 + dc]);
    }
}

// ---- fallback (R2 kernel, used only if d_ws is too small) ----
__global__ __launch_bounds__(512, 4)
void attn_kernel_fb(const float* __restrict__ q, const float* __restrict__ k,
                    const float* __restrict__ v, const int* __restrict__ mask,
                    float* __restrict__ out, float* __restrict__ attn)
{
    __shared__ __align__(16) _Float16 s_p[TQ][SSTRIDE];
    __shared__ float oacc[8][TQ * 16];
    __shared__ float s_inv[TQ];

    const int b = blockIdx.y, q0 = blockIdx.x * TQ, tid = threadIdx.x;
    const int w = tid >> 6, lane = tid & 63, quad = lane >> 4, m16 = lane & 15;
    const float* kp = k + (size_t)b * LSEQ * DIM;
    const float* vp = v + (size_t)b * LSEQ * DIM;
    const float* qrow = q + ((size_t)b * LSEQ + q0 + m16) * DIM + quad * 8;
    h8 aq0 = cvt_h8(*(const f4*)(qrow),      *(const f4*)(qrow + 4));
    h8 aq1 = cvt_h8(*(const f4*)(qrow + 32), *(const f4*)(qrow + 36));

    for (int t = w; t < LSEQ / 16; t += 8) {
        const int c = t * 16;
        const float* krow = kp + (size_t)(c + m16) * DIM + quad * 8;
        h8 bk0 = cvt_h8(*(const f4*)(krow),      *(const f4*)(krow + 4));
        h8 bk1 = cvt_h8(*(const f4*)(krow + 32), *(const f4*)(krow + 36));
        f4 acc = {0.f, 0.f, 0.f, 0.f};
        acc = __builtin_amdgcn_mfma_f32_16x16x32_f16(aq0, bk0, acc, 0, 0, 0);
        acc = __builtin_amdgcn_mfma_f32_16x16x32_f16(aq1, bk1, acc, 0, 0, 0);
        #pragma unroll
        for (int r = 0; r < 4; ++r)
            s_p[quad * 4 + r][c + m16] = (_Float16)(acc[r] * 0.125f);
    }
    __syncthreads();

    #pragma unroll
    for (int rr = 0; rr < 2; ++rr) {
        const int row = 2 * w + rr;
        const int* mrow = mask + ((size_t)b * LSEQ + q0 + row) * LSEQ;
        i4t mv[8];
        #pragma unroll
        for (int j = 0; j < 8; ++j)
            mv[j] = __builtin_nontemporal_load((const i4t*)(mrow + lane * 4 + 256 * j));
        float sa = 0.f, sk = 0.f;
        h4 pk[8];
        #pragma unroll
        for (int j = 0; j < 8; ++j) {
            h4 hv = *(const h4*)(&s_p[row][lane * 4 + 256 * j]);
            #pragma unroll
            for (int e = 0; e < 4; ++e) {
                float p = __expf((float)hv[e]);
                sa += p;
                float pm = mv[j][e] ? 0.f : p;
                sk += pm;
                pk[j][e] = (_Float16)pm;
            }
        }
        #pragma unroll
        for (int off = 32; off >= 1; off >>= 1) {
            sa += __shfl_xor(sa, off);
            sk += __shfl_xor(sk, off);
        }
        const float inv_d = 1.f / (sk + EPSV * sa);
        if (lane == 0) s_inv[row] = inv_d;
        float* arow = attn + ((size_t)b * LSEQ + q0 + row) * LSEQ;
        #pragma unroll
        for (int j = 0; j < 8; ++j) {
            const int c = lane * 4 + 256 * j;
            *(h4*)(&s_p[row][c]) = pk[j];
            f4 pv;
            #pragma unroll
            for (int e = 0; e < 4; ++e) pv[e] = inv_d * (float)pk[j][e];
            __builtin_nontemporal_store(pv, (f4*)(&arow[c]));
        }
    }
    __syncthreads();

    {
        const int dt = w >> 1, kh_ = w & 1;
        f4 acc = {0.f, 0.f, 0.f, 0.f};
        for (int kb0 = kh_ * 1024; kb0 < kh_ * 1024 + 1024; kb0 += 32) {
            const int kk = kb0 + quad * 8;
            h8 af = *(const h8*)(&s_p[m16][kk]);
            const float* vcol = vp + (size_t)kk * DIM + dt * 16 + m16;
            h8 bf;
            #pragma unroll
            for (int j = 0; j < 8; ++j) bf[j] = (_Float16)vcol[j * DIM];
            acc = __builtin_amdgcn_mfma_f32_16x16x32_f16(af, bf, acc, 0, 0, 0);
        }
        #pragma unroll
        for (int r = 0; r < 4; ++r)
            oacc[w][(quad * 4 + r) * 16 + m16] = acc[r];
    }
    __syncthreads();

    float* ob = out + ((size_t)b * LSEQ + q0) * DIM;
    #pragma unroll
    for (int it = 0; it < 2; ++it) {
        const int idx = tid + it * 512;
        const int row = idx >> 6, d = idx & 63;
        const int dt2 = d >> 4, dc = d & 15;
        ob[row * DIM + d] = s_inv[row] *
            (oacc[2 * dt2][row * 16 + dc] + oacc[2 * dt2 + 1][row * 16 + dc]);
    }
}

extern "C" void kernel_launch(void* const* d_in, const int* in_sizes, int n_in,
                              void* d_out, int out_size, void* d_ws, size_t ws_size,
                              hipStream_t stream) {
    const float* q = (const float*)d_in[0];
    const float* k = (const float*)d_in[1];
    const float* v = (const float*)d_in[2];
    const int* mask = (const int*)d_in[3];
    float* out = (float*)d_out;
    float* attn = out + (size_t)BATCH * LSEQ * DIM;
    dim3 grid(LSEQ / TQ, BATCH);

    const size_t kv_elems = (size_t)BATCH * LSEQ * DIM;
    if (ws_size >= kv_elems * 2 * sizeof(_Float16)) {
        _Float16* kh = (_Float16*)d_ws;
        _Float16* vt = kh + kv_elems;
        cvt_k_kernel<<<kv_elems / 4 / 256, 256, 0, stream>>>(k, kh);
        tr_v_kernel<<<dim3(LSEQ / 64, BATCH), 256, 0, stream>>>(v, vt);
        attn_kernel<<<grid, 512, 0, stream>>>(q, kh, vt, mask, out, attn);
    } else {
        attn_kernel_fb<<<grid, 512, 0, stream>>>(q, k, v, mask, out, attn);
    }
}